// Round 3
// baseline (2948.678 us; speedup 1.0000x reference)
//
#include <hip/hip_runtime.h>

#define NPTS 8192
#define NB 8
#define NS 2048
#define NK 32
#define C0 67
#define NTOT (NB*NS*NK)   // 524288 rows
#define NCONS 248         // consumer blocks
#define NHALF 496         // consumer half-blocks (2 per block)
#define NITER 34          // ceil(16384/496)

typedef __attribute__((ext_vector_type(2))) float f32x2;

// ---- DPP wave64 reduce helpers ---------------------------------------------
template <int CTRL, int ROWM>
__device__ __forceinline__ float dpp_fmax_step(float x) {
  int yi = __builtin_amdgcn_update_dpp(__float_as_int(x), __float_as_int(x),
                                       CTRL, ROWM, 0xf, false);
  return fmaxf(x, __int_as_float(yi));
}
template <int CTRL, int ROWM>
__device__ __forceinline__ unsigned dpp_umin_step(unsigned x) {
  unsigned y = (unsigned)__builtin_amdgcn_update_dpp((int)x, (int)x,
                                                     CTRL, ROWM, 0xf, false);
  return (y < x) ? y : x;
}
__device__ __forceinline__ float wave_max_f32(float v) {
  v = dpp_fmax_step<0x111, 0xf>(v);
  v = dpp_fmax_step<0x112, 0xf>(v);
  v = dpp_fmax_step<0x114, 0xf>(v);
  v = dpp_fmax_step<0x118, 0xf>(v);
  v = dpp_fmax_step<0x142, 0xa>(v);
  v = dpp_fmax_step<0x143, 0xc>(v);
  return v;
}
__device__ __forceinline__ unsigned wave_min_u32(unsigned v) {
  v = dpp_umin_step<0x111, 0xf>(v);
  v = dpp_umin_step<0x112, 0xf>(v);
  v = dpp_umin_step<0x114, 0xf>(v);
  v = dpp_umin_step<0x118, 0xf>(v);
  v = dpp_umin_step<0x142, 0xa>(v);
  v = dpp_umin_step<0x143, 0xc>(v);
  return v;
}

// ===========================================================================
// Block = 512 threads everywhere.
// Producers (blocks 0..7): 8 waves on one batch -> 2 waves/SIMD so the two
// instruction streams hide each other's dependency stalls (R2 showed the
// 4-wave producer is stall-bound at IPC~0.26, insensitive to VALU cuts).
// Consumers (blocks 8..255): two independent 256-thread halves per block,
// each identical to the proven 256-thread consumer.
// ===========================================================================
union SMemA {
  struct {
    float sx[NPTS], sy[NPTS], sz[NPTS];
    float snx[NS], sny[NS], snz[NS];
    uint2 slotVN[2][8];
  } fps;
  struct {
    float w0t[C0*64];
    float feat[2][C0*32];
    int   bq[2][4][32];
    int   bqc[2][4];
    int   s_idx[2][32];
    float s_c[2][3];
  } con;
};

__global__ __launch_bounds__(512, 2) void k_stage1A(
    const float* __restrict__ xyz, const float* __restrict__ pts,
    const float* __restrict__ w0, const float* __restrict__ g0,
    const float* __restrict__ be0,
    float* __restrict__ newxyz, float* __restrict__ pp,
    float* __restrict__ x0, float* __restrict__ part,
    float* __restrict__ statsF, unsigned* __restrict__ sync) {
  __shared__ __align__(16) SMemA sm;
  __shared__ int s_last;
  const int tid = threadIdx.x;
  unsigned* prog = sync;           // [0..7] zeroed by memset
  unsigned* ctr0 = sync + 8;

  if (blockIdx.x < NB) {
    // ===================== PRODUCER: FPS (8 waves, 16 pts/thread) ==========
    const int b = blockIdx.x;
    const int wv = tid >> 6, lane = tid & 63;   // wv 0..7
    const float* Xb = xyz + (size_t)b * NPTS * 3;
    f32x2 px2[8], py2[8], pz2[8], mind2[8];
#pragma unroll
    for (int i = 0; i < 8; i++) {
      int n0 = ((2*i) << 9) | tid;       // global point index = slot*512+tid
      int n1 = ((2*i+1) << 9) | tid;
      float ax = Xb[n0*3+0], ay = Xb[n0*3+1], az = Xb[n0*3+2];
      float bx2 = Xb[n1*3+0], by2 = Xb[n1*3+1], bz2 = Xb[n1*3+2];
      px2[i].x = ax;  px2[i].y = bx2;
      py2[i].x = ay;  py2[i].y = by2;
      pz2[i].x = az;  pz2[i].y = bz2;
      sm.fps.sx[n0]=ax;  sm.fps.sy[n0]=ay;  sm.fps.sz[n0]=az;
      sm.fps.sx[n1]=bx2; sm.fps.sy[n1]=by2; sm.fps.sz[n1]=bz2;
      pp[b*NPTS + n0] = __fadd_rn(__fadd_rn(__fmul_rn(ax,ax), __fmul_rn(ay,ay)), __fmul_rn(az,az));
      pp[b*NPTS + n1] = __fadd_rn(__fadd_rn(__fmul_rn(bx2,bx2), __fmul_rn(by2,by2)), __fmul_rn(bz2,bz2));
      mind2[i].x = 1e10f; mind2[i].y = 1e10f;
    }
    __syncthreads();
    float lx = sm.fps.sx[0], ly = sm.fps.sy[0], lz = sm.fps.sz[0];
    if (tid == 0) { sm.fps.snx[0]=lx; sm.fps.sny[0]=ly; sm.fps.snz[0]=lz; }
    for (int s = 1; s < NS; s++) {
#pragma clang fp contract(off)
      f32x2 lxx = {lx, lx}, lyy = {ly, ly}, lzz = {lz, lz};
      f32x2 m16[8];
#pragma unroll
      for (int i = 0; i < 8; i++) {
        f32x2 dx = px2[i] - lxx;
        f32x2 dy = py2[i] - lyy;
        f32x2 dz = pz2[i] - lzz;
        f32x2 d  = (dx*dx + dy*dy) + dz*dz;   // rn mul/add, no fma (contract off)
        f32x2 m;
        m.x = fminf(mind2[i].x, d.x);
        m.y = fminf(mind2[i].y, d.y);
        mind2[i] = m;
        m16[i] = m;
      }
      // balanced max tree (exact op -> association-order free)
#pragma unroll
      for (int st = 4; st >= 1; st >>= 1)
#pragma unroll
        for (int i = 0; i < st; i++) {
          m16[i].x = fmaxf(m16[i].x, m16[i+st].x);
          m16[i].y = fmaxf(m16[i].y, m16[i+st].y);
        }
      float v = fmaxf(m16[0].x, m16[0].y);
      float vr = wave_max_f32(v);
      float wmax = __int_as_float(__builtin_amdgcn_readlane(__float_as_int(vr), 63));
      // first slot (0..15) with mind==v : packed-compare + min-tree
      unsigned kt[8];
#pragma unroll
      for (int i = 0; i < 8; i++) {
        unsigned c = (mind2[i].y == v) ? (unsigned)(2*i+1) : 63u;
        kt[i] = (mind2[i].x == v) ? (unsigned)(2*i) : c;
      }
#pragma unroll
      for (int st = 4; st >= 1; st >>= 1)
#pragma unroll
        for (int i = 0; i < st; i++)
          kt[i] = (kt[i] < kt[i+st]) ? kt[i] : kt[i+st];
      // candidate n = global index (slot<<9)|tid -> u32-min == first-occurrence
      unsigned ncand = (v == wmax) ? ((kt[0] << 9) | (unsigned)tid) : 0xffffffffu;
      unsigned nr = wave_min_u32(ncand);
      int buf = s & 1;
      if (lane == 63) sm.fps.slotVN[buf][wv] = make_uint2(__float_as_uint(vr), nr);
      __syncthreads();
      // ---- 8-slot tournament (lexicographic on (-v, n); keys distinct) ----
      uint4 q0 = *(const uint4*)&sm.fps.slotVN[buf][0];
      uint4 q1 = *(const uint4*)&sm.fps.slotVN[buf][2];
      uint4 q2 = *(const uint4*)&sm.fps.slotVN[buf][4];
      uint4 q3 = *(const uint4*)&sm.fps.slotVN[buf][6];
      unsigned v0 = q0.x, n0_ = q0.y;
      if (q0.z > v0 || (q0.z == v0 && q0.w < n0_)) { v0 = q0.z; n0_ = q0.w; }
      unsigned v1 = q1.x, n1_ = q1.y;
      if (q1.z > v1 || (q1.z == v1 && q1.w < n1_)) { v1 = q1.z; n1_ = q1.w; }
      unsigned v2 = q2.x, n2_ = q2.y;
      if (q2.z > v2 || (q2.z == v2 && q2.w < n2_)) { v2 = q2.z; n2_ = q2.w; }
      unsigned v3 = q3.x, n3_ = q3.y;
      if (q3.z > v3 || (q3.z == v3 && q3.w < n3_)) { v3 = q3.z; n3_ = q3.w; }
      if (v1 > v0 || (v1 == v0 && n1_ < n0_)) { v0 = v1; n0_ = n1_; }
      if (v3 > v2 || (v3 == v2 && n3_ < n2_)) { v2 = v3; n2_ = n3_; }
      if (v2 > v0 || (v2 == v0 && n2_ < n0_)) { v0 = v2; n0_ = n2_; }
      int n = (int)n0_;
      lx = sm.fps.sx[n]; ly = sm.fps.sy[n]; lz = sm.fps.sz[n];
      if (tid == 0) { sm.fps.snx[s]=lx; sm.fps.sny[s]=ly; sm.fps.snz[s]=lz; }
      if ((s & 63) == 63) {
        __syncthreads();
        int cs = s - 63;
        if (tid < 192) {
          int e = cs + tid / 3, comp = tid - (tid / 3) * 3;
          float vvv = (comp == 0) ? sm.fps.snx[e] : ((comp == 1) ? sm.fps.sny[e] : sm.fps.snz[e]);
          newxyz[((size_t)b*NS + cs)*3 + tid] = vvv;
        }
        __syncthreads();
        if (tid == 0) {
          __threadfence();
          __hip_atomic_store(&prog[b], (unsigned)(s + 1), __ATOMIC_RELEASE, __HIP_MEMORY_SCOPE_AGENT);
        }
      }
    }
  } else {
    // ========== CONSUMER: two 256-thread halves, 2 centroids/iter ==========
    const int cb = blockIdx.x - NB;          // 0..247
    const int h = tid >> 8;                  // half 0/1
    const int t = tid & 255;                 // local tid within half
    const int wv = (tid >> 6) & 3, lane = tid & 63;
    float* w0t = sm.con.w0t;
    float* feat = sm.con.feat[h];
    for (int i = tid; i < C0*64; i += 512) { int j = i >> 6, c = i & 63; w0t[i] = w0[c*C0 + j]; }
    int rt = t & 7, ct = t >> 3;
    float s0[2] = {0,0}, q0s[2] = {0,0};
    for (int it = 0; it < NITER; it++) {
      int e = (cb << 1) + h + NHALF * it;
      bool active = (e < NB*NS);
      int s = e >> 3, b = e & 7;
      size_t row = (size_t)b * NS + s;
      if (active && t == 0) {
        while ((int)__hip_atomic_load(&prog[b], __ATOMIC_ACQUIRE, __HIP_MEMORY_SCOPE_AGENT) <= s)
          __builtin_amdgcn_s_sleep(32);
        __threadfence();
      }
      __syncthreads();
      const float* c3 = newxyz + row * 3;
      float cx = 0.f, cy = 0.f, cz = 0.f, qq = 0.f;
      if (active) {
        cx = c3[0]; cy = c3[1]; cz = c3[2];
        qq = __fadd_rn(__fadd_rn(__fmul_rn(cx,cx), __fmul_rn(cy,cy)), __fmul_rn(cz,cz));
        const float* Xb = xyz + (size_t)b * NPTS * 3;
        const float* Pb = pp + b * NPTS;
        int cnt = 0;
        int base = wv << 11;
        for (int j0 = base; j0 < base + 2048; j0 += 64) {
          int n = j0 + lane;
          float x = Xb[n*3+0], y = Xb[n*3+1], z = Xb[n*3+2];
          float dot = __fadd_rn(__fadd_rn(__fmul_rn(cx,x), __fmul_rn(cy,y)), __fmul_rn(cz,z));
          float d2 = __fsub_rn(__fadd_rn(qq, Pb[n]), __fmul_rn(2.0f, dot));
          bool in = (d2 <= 0.0625f);
          unsigned long long bal = __ballot(in);
          if (in) {
            int pos = cnt + (int)__popcll(bal & ((1ull << lane) - 1ull));
            if (pos < NK) sm.con.bq[h][wv][pos] = n;
          }
          cnt += (int)__popcll(bal);
          if (cnt >= NK) break;
        }
        if (lane == 0) sm.con.bqc[h][wv] = (cnt < NK) ? cnt : NK;
      }
      __syncthreads();
      if (active) {
        if (t < NK) {
          int l0 = sm.con.bqc[h][0], l1 = sm.con.bqc[h][1], l2 = sm.con.bqc[h][2], l3 = sm.con.bqc[h][3];
          int t1 = l0 + l1, t2 = t1 + l2, t3 = t2 + l3;
          int j = t, v;
          if (j < l0)      v = sm.con.bq[h][0][j];
          else if (j < t1) v = sm.con.bq[h][1][j - l0];
          else if (j < t2) v = sm.con.bq[h][2][j - t1];
          else if (j < t3) v = sm.con.bq[h][3][j - t2];
          else {
            v = (l0 > 0) ? sm.con.bq[h][0][0] : (l1 > 0) ? sm.con.bq[h][1][0]
              : (l2 > 0) ? sm.con.bq[h][2][0] : (l3 > 0) ? sm.con.bq[h][3][0] : 0;
          }
          sm.con.s_idx[h][j] = v;
        }
        if (t >= 32 && t < 35) sm.con.s_c[h][t - 32] = c3[t - 32];
      }
      __syncthreads();
      if (active) {
        if (t < 32) {
          const float* p = &xyz[((size_t)b*NPTS + sm.con.s_idx[h][t])*3];
          feat[0*32+t] = p[0] - sm.con.s_c[h][0];
          feat[1*32+t] = p[1] - sm.con.s_c[h][1];
          feat[2*32+t] = p[2] - sm.con.s_c[h][2];
        }
        {
          int r_ = t & 31, cq_ = t >> 5;
          const float* pr = &pts[((size_t)b*NPTS + sm.con.s_idx[h][r_])*64 + cq_*8];
          float4 A_ = *(const float4*)pr;
          float4 B_ = *(const float4*)(pr + 4);
          feat[(3+cq_*8+0)*32 + r_] = A_.x;
          feat[(3+cq_*8+1)*32 + r_] = A_.y;
          feat[(3+cq_*8+2)*32 + r_] = A_.z;
          feat[(3+cq_*8+3)*32 + r_] = A_.w;
          feat[(3+cq_*8+4)*32 + r_] = B_.x;
          feat[(3+cq_*8+5)*32 + r_] = B_.y;
          feat[(3+cq_*8+6)*32 + r_] = B_.z;
          feat[(3+cq_*8+7)*32 + r_] = B_.w;
        }
      }
      __syncthreads();
      if (active) {
        float acc[4][2] = {};
        for (int j = 0; j < C0; j++) {
          float4 av = *(const float4*)&feat[j*32 + rt*4];
          float2 wvv = *(const float2*)&w0t[j*64 + ct*2];
          float aa[4] = {av.x, av.y, av.z, av.w};
#pragma unroll
          for (int r = 0; r < 4; r++) {
            acc[r][0] = fmaf(aa[r], wvv.x, acc[r][0]);
            acc[r][1] = fmaf(aa[r], wvv.y, acc[r][1]);
          }
        }
        // stream raw x0 (pre-BN) + accumulate stats
        float* dst = x0 + row * 2048;
#pragma unroll
        for (int r = 0; r < 4; r++)
#pragma unroll
          for (int u = 0; u < 2; u++) {
            float x = acc[r][u];
            dst[(rt*4+r)*64 + ct*2+u] = x;
            s0[u] += x; q0s[u] = fmaf(x, x, q0s[u]);
          }
      }
      __syncthreads();
    }
#pragma unroll
    for (int off = 1; off < 8; off <<= 1) {
#pragma unroll
      for (int u = 0; u < 2; u++) { s0[u] += __shfl_xor(s0[u], off, 64); q0s[u] += __shfl_xor(q0s[u], off, 64); }
    }
    if (rt == 0) {
#pragma unroll
      for (int u = 0; u < 2; u++) {
        size_t o = ((size_t)((cb << 1) + h) * 128 + ct*2 + u) * 2;
        part[o] = s0[u]; part[o+1] = q0s[u];
      }
    }
    // ---- fused fin0: last consumer block reduces partials -> statsF0 ----
    __threadfence();
    if (tid == 0) {
      unsigned old = __hip_atomic_fetch_add(ctr0, 1u, __ATOMIC_ACQ_REL, __HIP_MEMORY_SCOPE_AGENT);
      s_last = (old == NCONS - 1);
    }
    __syncthreads();
    if (s_last) {
      __threadfence();
      if (tid < 64) {
        float s = 0.f, q = 0.f;
        for (int k = 0; k < NHALF; k++) {
          s += part[((size_t)k * 128 + tid) * 2];
          q += part[((size_t)k * 128 + tid) * 2 + 1];
        }
        const float inv = 1.0f / (float)NTOT;
        float mean = s * inv;
        float var = q * inv - mean * mean;
        float a = g0[tid] / sqrtf(var + 1e-5f);
        float bb = be0[tid] - mean * a;
        statsF[tid*2] = a; statsF[tid*2 + 1] = bb;
      }
    }
  }
}

// L1 pass (path A): read x0, BN0+ReLU, L1 GEMM; store raw x1 IN PLACE over x0
// (group-exclusive ownership; x0 dead afterwards); stats1; fused fin1.
__global__ __launch_bounds__(256) void k_l1x(
    float* __restrict__ x0, const float* __restrict__ w1,
    const float* __restrict__ g1, const float* __restrict__ be1,
    float* __restrict__ statsF, float* __restrict__ part,
    unsigned* __restrict__ sync) {
  __shared__ __align__(16) float w1t[64*64];
  __shared__ __align__(16) float x0n[64*32];
  __shared__ float sF[128];
  __shared__ int s_last;
  unsigned* ctr1 = sync + 9;
  int tid = threadIdx.x;
  for (int t = tid; t < 64*64; t += 256) { int j = t >> 6, c = t & 63; w1t[t] = w1[c*64 + j]; }
  if (tid < 64) { sF[tid] = statsF[tid*2]; sF[64+tid] = statsF[tid*2+1]; }
  int rt = tid & 7, ct = tid >> 3;
  float s1[2] = {0,0}, q1[2] = {0,0};
  for (int g = 0; g < 32; g++) {
    size_t gid = (size_t)blockIdx.x * 32 + g;
    __syncthreads();   // protect x0n reuse
    float* src = x0 + gid * 2048;
#pragma unroll
    for (int i = 0; i < 2; i++) {
      int local = tid*8 + i*4;
      float4 v = *(const float4*)(src + local);
      int row = local >> 6, col = local & 63;
      x0n[(col+0)*32+row] = fmaxf(0.f, fmaf(v.x, sF[col+0], sF[64+col+0]));
      x0n[(col+1)*32+row] = fmaxf(0.f, fmaf(v.y, sF[col+1], sF[64+col+1]));
      x0n[(col+2)*32+row] = fmaxf(0.f, fmaf(v.z, sF[col+2], sF[64+col+2]));
      x0n[(col+3)*32+row] = fmaxf(0.f, fmaf(v.w, sF[col+3], sF[64+col+3]));
    }
    __syncthreads();
    float acc[4][2] = {};
    for (int j = 0; j < 64; j++) {
      float4 av = *(const float4*)&x0n[j*32 + rt*4];
      float2 wv = *(const float2*)&w1t[j*64 + ct*2];
      float aa[4] = {av.x, av.y, av.z, av.w};
#pragma unroll
      for (int r = 0; r < 4; r++) {
        acc[r][0] = fmaf(aa[r], wv.x, acc[r][0]);
        acc[r][1] = fmaf(aa[r], wv.y, acc[r][1]);
      }
    }
    // store raw x1 in place (consumed only by k_l2x) + stats
#pragma unroll
    for (int r = 0; r < 4; r++)
#pragma unroll
      for (int u = 0; u < 2; u++) {
        float x = acc[r][u];
        src[(rt*4+r)*64 + ct*2+u] = x;
        s1[u] += x; q1[u] = fmaf(x, x, q1[u]);
      }
  }
#pragma unroll
  for (int off = 1; off < 8; off <<= 1) {
#pragma unroll
    for (int u = 0; u < 2; u++) { s1[u] += __shfl_xor(s1[u], off, 64); q1[u] += __shfl_xor(q1[u], off, 64); }
  }
  if (rt == 0) {
#pragma unroll
    for (int u = 0; u < 2; u++) {
      size_t o = ((size_t)blockIdx.x * 128 + ct*2 + u) * 2;
      part[o] = s1[u]; part[o+1] = q1[u];
    }
  }
  __threadfence();
  if (tid == 0) {
    unsigned old = __hip_atomic_fetch_add(ctr1, 1u, __ATOMIC_ACQ_REL, __HIP_MEMORY_SCOPE_AGENT);
    s_last = (old == 511);
  }
  __syncthreads();
  if (s_last) {
    __threadfence();
    if (tid < 64) {
      float s = 0.f, q = 0.f;
      for (int k = 0; k < 512; k++) {
        s += part[((size_t)k * 128 + tid) * 2];
        q += part[((size_t)k * 128 + tid) * 2 + 1];
      }
      const float inv = 1.0f / (float)NTOT;
      float mean = s * inv;
      float var = q * inv - mean * mean;
      float a = g1[tid] / sqrtf(var + 1e-5f);
      float bb = be1[tid] - mean * a;
      statsF[(128 + tid)*2] = a; statsF[(128 + tid)*2 + 1] = bb;
    }
  }
}

// L2 pass (path A, SLIM): read raw x1 (in x0 buffer), BN1+ReLU, L2 GEMM only;
// stats2 + per-group max/min; fused fin2.
__global__ __launch_bounds__(256) void k_l2x(
    const float* __restrict__ x1, const float* __restrict__ w2,
    const float* __restrict__ g2, const float* __restrict__ be2,
    float* __restrict__ statsF, float* __restrict__ part,
    float* __restrict__ maxb, float* __restrict__ minb,
    unsigned* __restrict__ sync) {
  __shared__ __align__(16) float w2t[64*128];
  __shared__ __align__(16) float x1n[64*32];
  __shared__ float sF[128];
  __shared__ int s_last;
  unsigned* ctr2 = sync + 10;
  int tid = threadIdx.x;
  for (int t = tid; t < 64*128; t += 256) { int j = t >> 7, c = t & 127; w2t[t] = w2[c*64 + j]; }
  if (tid < 64) { sF[tid] = statsF[(128+tid)*2]; sF[64+tid] = statsF[(128+tid)*2+1]; }
  int rt = tid & 7, ct = tid >> 3;
  float s2[4] = {0,0,0,0}, q2[4] = {0,0,0,0};
  for (int g = 0; g < 64; g++) {
    size_t gid = (size_t)blockIdx.x * 64 + g;
    __syncthreads();   // protect x1n reuse; covers sF/w2t on first iter
    const float* src = x1 + gid * 2048;
#pragma unroll
    for (int i = 0; i < 2; i++) {
      int local = tid*8 + i*4;
      float4 v = *(const float4*)(src + local);
      int row = local >> 6, col = local & 63;
      x1n[(col+0)*32+row] = fmaxf(0.f, fmaf(v.x, sF[col+0], sF[64+col+0]));
      x1n[(col+1)*32+row] = fmaxf(0.f, fmaf(v.y, sF[col+1], sF[64+col+1]));
      x1n[(col+2)*32+row] = fmaxf(0.f, fmaf(v.z, sF[col+2], sF[64+col+2]));
      x1n[(col+3)*32+row] = fmaxf(0.f, fmaf(v.w, sF[col+3], sF[64+col+3]));
    }
    __syncthreads();
    float acc[4][4] = {};
    for (int j = 0; j < 64; j++) {
      float4 av = *(const float4*)&x1n[j*32 + rt*4];
      float4 wvv = *(const float4*)&w2t[j*128 + ct*4];
      float aa[4] = {av.x, av.y, av.z, av.w};
      float ww[4] = {wvv.x, wvv.y, wvv.z, wvv.w};
#pragma unroll
      for (int r = 0; r < 4; r++)
#pragma unroll
        for (int u = 0; u < 4; u++) acc[r][u] = fmaf(aa[r], ww[u], acc[r][u]);
    }
    float mx[4], mn[4];
#pragma unroll
    for (int u = 0; u < 4; u++) {
      float x0v = acc[0][u], x1v = acc[1][u], x2v = acc[2][u], x3v = acc[3][u];
      s2[u] += ((x0v + x1v) + (x2v + x3v));
      q2[u] = fmaf(x0v, x0v, q2[u]); q2[u] = fmaf(x1v, x1v, q2[u]);
      q2[u] = fmaf(x2v, x2v, q2[u]); q2[u] = fmaf(x3v, x3v, q2[u]);
      mx[u] = fmaxf(fmaxf(x0v, x1v), fmaxf(x2v, x3v));
      mn[u] = fminf(fminf(x0v, x1v), fminf(x2v, x3v));
    }
#pragma unroll
    for (int off = 1; off < 8; off <<= 1) {
#pragma unroll
      for (int u = 0; u < 4; u++) {
        mx[u] = fmaxf(mx[u], __shfl_xor(mx[u], off, 64));
        mn[u] = fminf(mn[u], __shfl_xor(mn[u], off, 64));
      }
    }
    if (rt == 0) {
#pragma unroll
      for (int u = 0; u < 4; u++) {
        maxb[gid*128 + ct*4 + u] = mx[u];
        minb[gid*128 + ct*4 + u] = mn[u];
      }
    }
  }
#pragma unroll
  for (int off = 1; off < 8; off <<= 1) {
#pragma unroll
    for (int u = 0; u < 4; u++) { s2[u] += __shfl_xor(s2[u], off, 64); q2[u] += __shfl_xor(q2[u], off, 64); }
  }
  if (rt == 0) {
#pragma unroll
    for (int u = 0; u < 4; u++) {
      size_t o = ((size_t)blockIdx.x * 128 + ct*4 + u) * 2;
      part[o] = s2[u]; part[o+1] = q2[u];
    }
  }
  __threadfence();
  if (tid == 0) {
    unsigned old = __hip_atomic_fetch_add(ctr2, 1u, __ATOMIC_ACQ_REL, __HIP_MEMORY_SCOPE_AGENT);
    s_last = (old == 255);
  }
  __syncthreads();
  if (s_last) {
    __threadfence();
    if (tid < 128) {
      float s = 0.f, q = 0.f;
      for (int k = 0; k < 256; k++) {
        s += part[((size_t)k * 128 + tid) * 2];
        q += part[((size_t)k * 128 + tid) * 2 + 1];
      }
      const float inv = 1.0f / (float)NTOT;
      float mean = s * inv;
      float var = q * inv - mean * mean;
      float a = g2[tid] / sqrtf(var + 1e-5f);
      float bb = be2[tid] - mean * a;
      statsF[(256 + tid)*2] = a; statsF[(256 + tid)*2 + 1] = bb;
    }
  }
}

// Pool epilogue: pooled = relu(a*X + beta), X = a>=0 ? max : min.
__global__ __launch_bounds__(256) void k_pool(const float* __restrict__ maxb,
                                              const float* __restrict__ minb,
                                              const float* __restrict__ statsF,
                                              float* __restrict__ outp) {
  int t = blockIdx.x * 256 + threadIdx.x;
  int c = t & 127;
  float a  = statsF[(2*128 + c)*2];
  float bb = statsF[(2*128 + c)*2 + 1];
  float X = (a >= 0.f) ? maxb[t] : minb[t];
  outp[t] = fmaxf(0.f, fmaf(a, X, bb));
}

// ---------------------------------------------------------------------------
extern "C" void kernel_launch(void* const* d_in, const int* in_sizes, int n_in,
                              void* d_out, int out_size, void* d_ws, size_t ws_size,
                              hipStream_t stream) {
  (void)in_sizes; (void)n_in; (void)out_size; (void)ws_size;
  const float* xyz = (const float*)d_in[0];
  const float* pts = (const float*)d_in[1];
  const float* w0  = (const float*)d_in[2];
  const float* g0  = (const float*)d_in[4];
  const float* be0 = (const float*)d_in[5];
  const float* w1  = (const float*)d_in[6];
  const float* g1  = (const float*)d_in[8];
  const float* be1 = (const float*)d_in[9];
  const float* w2  = (const float*)d_in[10];
  const float* g2  = (const float*)d_in[12];
  const float* be2 = (const float*)d_in[13];

  float* out = (float*)d_out;
  float* newxyz = out;
  float* pooled = out + (size_t)NB*NS*3;

  float* ws = (float*)d_ws;
  // Path A layout (proven to fit): pp | x0 | part | statsF | maxb | minb | sync
  float* pp     = ws;                                  // 65536
  float* x0     = ws + 65536;                          // 33,554,432 (x1 in place later)
  float* part   = x0 + 33554432;                       // 131072 (496*128*2 = 126976 used)
  float* statsF = part + 131072;                       // 768
  float* maxb   = statsF + 768;                        // 2,097,152
  float* minb   = maxb + 2097152;                      // 2,097,152
  unsigned* sync = (unsigned*)(minb + 2097152);        // prog[8], ctr0..2

  hipMemsetAsync(sync, 0, 64, stream);
  k_stage1A<<<256, 512, 0, stream>>>(xyz, pts, w0, g0, be0,
                                     newxyz, pp, x0, part, statsF, sync);
  k_l1x<<<512, 256, 0, stream>>>(x0, w1, g1, be1, statsF, part, sync);
  k_l2x<<<256, 256, 0, stream>>>(x0, w2, g2, be2, statsF, part,
                                 maxb, minb, sync);
  k_pool<<<8192, 256, 0, stream>>>(maxb, minb, statsF, pooled);
}

// Round 4
// 2665.430 us; speedup vs baseline: 1.1063x; 1.1063x over previous
//
#include <hip/hip_runtime.h>

#define NPTS 8192
#define NB 8
#define NS 2048
#define NK 32
#define C0 67
#define NTOT (NB*NS*NK)   // 524288 rows
#define NCONS 248

typedef __attribute__((ext_vector_type(2))) float f32x2;
typedef __attribute__((ext_vector_type(4))) unsigned u32x4;

// ---- DPP wave64 reduce helpers ---------------------------------------------
template <int CTRL, int ROWM>
__device__ __forceinline__ float dpp_fmax_step(float x) {
  int yi = __builtin_amdgcn_update_dpp(__float_as_int(x), __float_as_int(x),
                                       CTRL, ROWM, 0xf, false);
  return fmaxf(x, __int_as_float(yi));
}
template <int CTRL, int ROWM>
__device__ __forceinline__ unsigned dpp_umin_step(unsigned x) {
  unsigned y = (unsigned)__builtin_amdgcn_update_dpp((int)x, (int)x,
                                                     CTRL, ROWM, 0xf, false);
  return (y < x) ? y : x;
}
__device__ __forceinline__ float wave_max_f32(float v) {
  v = dpp_fmax_step<0x111, 0xf>(v);
  v = dpp_fmax_step<0x112, 0xf>(v);
  v = dpp_fmax_step<0x114, 0xf>(v);
  v = dpp_fmax_step<0x118, 0xf>(v);
  v = dpp_fmax_step<0x142, 0xa>(v);
  v = dpp_fmax_step<0x143, 0xc>(v);
  return v;
}
__device__ __forceinline__ unsigned wave_min_u32(unsigned v) {
  v = dpp_umin_step<0x111, 0xf>(v);
  v = dpp_umin_step<0x112, 0xf>(v);
  v = dpp_umin_step<0x114, 0xf>(v);
  v = dpp_umin_step<0x118, 0xf>(v);
  v = dpp_umin_step<0x142, 0xa>(v);
  v = dpp_umin_step<0x143, 0xc>(v);
  return v;
}

// ===========================================================================
// ============================ PATH A (streamed x0) =========================
// ===========================================================================
union SMemA {
  struct {
    float sx[NPTS], sy[NPTS], sz[NPTS];
    float snx[NS], sny[NS], snz[NS];
    u32x4 slot16[2][4];   // [buf][wave] = {v_bits, n, tag(step), 0}
  } fps;
  struct {
    float w0t[C0*64];
    float feat[C0*32];
    int   bq[4][32];
    int   bqc[4];
    int   s_idx[32];
    float s_c[3];
  } con;
};

// Stage1: FPS producers (blocks 0..7) + consumers (8..255).
// Producer per-step sync: step-tagged LDS mailbox (ds_write_b128 + poll)
// replacing __syncthreads -- removes lgkmcnt(0) drain + s_barrier from the
// serial critical path (R3 showed sync section scales w/ waves = dominant).
// Distance math unchanged: packed rn mul/add, contract(off) -> bit-exact.
__global__ __launch_bounds__(256, 1) void k_stage1A(
    const float* __restrict__ xyz, const float* __restrict__ pts,
    const float* __restrict__ w0, const float* __restrict__ g0,
    const float* __restrict__ be0,
    float* __restrict__ newxyz, float* __restrict__ pp,
    float* __restrict__ x0, float* __restrict__ part,
    float* __restrict__ statsF, unsigned* __restrict__ sync) {
  __shared__ __align__(16) SMemA sm;
  __shared__ int s_last;
  const int tid = threadIdx.x;
  unsigned* prog = sync;           // [0..7] zeroed by memset
  unsigned* ctr0 = sync + 8;

  if (blockIdx.x < NB) {
    // ===================== PRODUCER: FPS =====================
    const int b = blockIdx.x;
    const int wv = tid >> 6, lane = tid & 63;
    const float* Xb = xyz + (size_t)b * NPTS * 3;
    f32x2 px2[16], py2[16], pz2[16], mind2[16];
#pragma unroll
    for (int i = 0; i < 16; i++) {
      int n0 = ((2*i) << 8) | tid;
      int n1 = ((2*i+1) << 8) | tid;
      float ax = Xb[n0*3+0], ay = Xb[n0*3+1], az = Xb[n0*3+2];
      float bx2 = Xb[n1*3+0], by2 = Xb[n1*3+1], bz2 = Xb[n1*3+2];
      px2[i].x = ax;  px2[i].y = bx2;
      py2[i].x = ay;  py2[i].y = by2;
      pz2[i].x = az;  pz2[i].y = bz2;
      sm.fps.sx[n0]=ax;  sm.fps.sy[n0]=ay;  sm.fps.sz[n0]=az;
      sm.fps.sx[n1]=bx2; sm.fps.sy[n1]=by2; sm.fps.sz[n1]=bz2;
      pp[b*NPTS + n0] = __fadd_rn(__fadd_rn(__fmul_rn(ax,ax), __fmul_rn(ay,ay)), __fmul_rn(az,az));
      pp[b*NPTS + n1] = __fadd_rn(__fadd_rn(__fmul_rn(bx2,bx2), __fmul_rn(by2,by2)), __fmul_rn(bz2,bz2));
      mind2[i].x = 1e10f; mind2[i].y = 1e10f;
    }
    // init mailbox tags to a value no step uses (steps are 1..2047)
    if (tid < 8) {
      u32x4 z; z[0] = 0; z[1] = 0; z[2] = 0xffffffffu; z[3] = 0;
      sm.fps.slot16[tid >> 2][tid & 3] = z;
    }
    __syncthreads();
    float lx = sm.fps.sx[0], ly = sm.fps.sy[0], lz = sm.fps.sz[0];
    if (tid == 0) { sm.fps.snx[0]=lx; sm.fps.sny[0]=ly; sm.fps.snz[0]=lz; }
    for (int s = 1; s < NS; s++) {
#pragma clang fp contract(off)
      f32x2 lxx = {lx, lx}, lyy = {ly, ly}, lzz = {lz, lz};
      f32x2 m16[16];
#pragma unroll
      for (int i = 0; i < 16; i++) {
        f32x2 dx = px2[i] - lxx;
        f32x2 dy = py2[i] - lyy;
        f32x2 dz = pz2[i] - lzz;
        f32x2 d  = (dx*dx + dy*dy) + dz*dz;   // rn mul/add, no fma (contract off)
        f32x2 m;
        m.x = fminf(mind2[i].x, d.x);
        m.y = fminf(mind2[i].y, d.y);
        mind2[i] = m;
        m16[i] = m;
      }
      // balanced max tree (exact op -> association-order free)
#pragma unroll
      for (int st = 8; st >= 1; st >>= 1)
#pragma unroll
        for (int i = 0; i < st; i++) {
          m16[i].x = fmaxf(m16[i].x, m16[i+st].x);
          m16[i].y = fmaxf(m16[i].y, m16[i+st].y);
        }
      float v = fmaxf(m16[0].x, m16[0].y);
      float vr = wave_max_f32(v);
      float wmax = __int_as_float(__builtin_amdgcn_readlane(__float_as_int(vr), 63));
      // first k (0..31) with mind==v : packed-compare + depth-4 min-tree
      // (exactness-proven vs serial chain in R1/R2: identical FPS selections)
      unsigned kt[16];
#pragma unroll
      for (int i = 0; i < 16; i++) {
        unsigned c = (mind2[i].y == v) ? (unsigned)(2*i+1) : 63u;
        kt[i] = (mind2[i].x == v) ? (unsigned)(2*i) : c;
      }
#pragma unroll
      for (int st = 8; st >= 1; st >>= 1)
#pragma unroll
        for (int i = 0; i < st; i++)
          kt[i] = (kt[i] < kt[i+st]) ? kt[i] : kt[i+st];
      unsigned ncand = (v == wmax) ? ((kt[0] << 8) | (unsigned)tid) : 0xffffffffu;
      unsigned nr = wave_min_u32(ncand);
      const int buf = s & 1;
      // ---- mailbox write: single b128 packet {v, n, tag=s, 0}; no drain ----
      if (lane == 63) {
        u32x4 pkt;
        pkt[0] = __float_as_uint(vr); pkt[1] = nr; pkt[2] = (unsigned)s; pkt[3] = 0;
        unsigned wa = (unsigned)(uintptr_t)&sm.fps.slot16[buf][wv];
        asm volatile("ds_write_b128 %0, %1" :: "v"(wa), "v"(pkt) : "memory");
      }
      // ---- poll all 4 packets until every tag == s (replaces barrier) ----
      unsigned ra = (unsigned)(uintptr_t)&sm.fps.slot16[buf][0];
      u32x4 r0, r1, r2, r3;
      for (;;) {
        asm volatile("ds_read_b128 %0, %4 offset:0\n\t"
                     "ds_read_b128 %1, %4 offset:16\n\t"
                     "ds_read_b128 %2, %4 offset:32\n\t"
                     "ds_read_b128 %3, %4 offset:48\n\t"
                     "s_waitcnt lgkmcnt(0)"
                     : "=v"(r0), "=v"(r1), "=v"(r2), "=v"(r3)
                     : "v"(ra) : "memory");
        __builtin_amdgcn_sched_barrier(0);
        if ((((r0[2] ^ (unsigned)s) | (r1[2] ^ (unsigned)s)) |
             ((r2[2] ^ (unsigned)s) | (r3[2] ^ (unsigned)s))) == 0) break;
      }
      // ---- tournament (lexicographic on (-v, n); fp bits compare ok: v>=0) --
      unsigned bx = r0[0], by = r0[1];
      if (r1[0] > bx || (r1[0] == bx && r1[1] < by)) { bx = r1[0]; by = r1[1]; }
      if (r2[0] > bx || (r2[0] == bx && r2[1] < by)) { bx = r2[0]; by = r2[1]; }
      if (r3[0] > bx || (r3[0] == bx && r3[1] < by)) { bx = r3[0]; by = r3[1]; }
      int n = (int)by;
      lx = sm.fps.sx[n]; ly = sm.fps.sy[n]; lz = sm.fps.sz[n];
      if (tid == 0) { sm.fps.snx[s]=lx; sm.fps.sny[s]=ly; sm.fps.snz[s]=lz; }
      if ((s & 63) == 63) {
        __syncthreads();
        int cs = s - 63;
        if (tid < 192) {
          int e = cs + tid / 3, comp = tid - (tid / 3) * 3;
          float vvv = (comp == 0) ? sm.fps.snx[e] : ((comp == 1) ? sm.fps.sny[e] : sm.fps.snz[e]);
          newxyz[((size_t)b*NS + cs)*3 + tid] = vvv;
        }
        __syncthreads();
        if (tid == 0) {
          __threadfence();
          __hip_atomic_store(&prog[b], (unsigned)(s + 1), __ATOMIC_RELEASE, __HIP_MEMORY_SCOPE_AGENT);
        }
      }
    }
  } else {
    // ===================== CONSUMER: BQ + L0 -> x0 stream =====================
    const int cb = blockIdx.x - NB;          // 0..247
    const int wv = tid >> 6, lane = tid & 63;
    float* w0t = sm.con.w0t;
    float* feat = sm.con.feat;
    for (int t = tid; t < C0*64; t += 256) { int j = t >> 6, c = t & 63; w0t[t] = w0[c*C0 + j]; }
    int rt = tid & 7, ct = tid >> 3;
    float s0[2] = {0,0}, q0[2] = {0,0};
    for (int it = 0; it <= 66; it++) {
      int e = cb + NCONS * it;
      if (e >= NB*NS) break;
      int s = e >> 3, b = e & 7;
      size_t row = (size_t)b * NS + s;
      if (tid == 0) {
        while ((int)__hip_atomic_load(&prog[b], __ATOMIC_ACQUIRE, __HIP_MEMORY_SCOPE_AGENT) <= s)
          __builtin_amdgcn_s_sleep(32);
        __threadfence();
      }
      __syncthreads();
      const float* c3 = newxyz + row * 3;
      float cx = c3[0], cy = c3[1], cz = c3[2];
      float qq = __fadd_rn(__fadd_rn(__fmul_rn(cx,cx), __fmul_rn(cy,cy)), __fmul_rn(cz,cz));
      const float* Xb = xyz + (size_t)b * NPTS * 3;
      const float* Pb = pp + b * NPTS;
      int cnt = 0;
      int base = wv << 11;
      for (int j0 = base; j0 < base + 2048; j0 += 64) {
        int n = j0 + lane;
        float x = Xb[n*3+0], y = Xb[n*3+1], z = Xb[n*3+2];
        float dot = __fadd_rn(__fadd_rn(__fmul_rn(cx,x), __fmul_rn(cy,y)), __fmul_rn(cz,z));
        float d2 = __fsub_rn(__fadd_rn(qq, Pb[n]), __fmul_rn(2.0f, dot));
        bool in = (d2 <= 0.0625f);
        unsigned long long bal = __ballot(in);
        if (in) {
          int pos = cnt + (int)__popcll(bal & ((1ull << lane) - 1ull));
          if (pos < NK) sm.con.bq[wv][pos] = n;
        }
        cnt += (int)__popcll(bal);
        if (cnt >= NK) break;
      }
      if (lane == 0) sm.con.bqc[wv] = (cnt < NK) ? cnt : NK;
      __syncthreads();
      if (tid < NK) {
        int l0 = sm.con.bqc[0], l1 = sm.con.bqc[1], l2 = sm.con.bqc[2], l3 = sm.con.bqc[3];
        int t1 = l0 + l1, t2 = t1 + l2, t3 = t2 + l3;
        int j = tid, v;
        if (j < l0)      v = sm.con.bq[0][j];
        else if (j < t1) v = sm.con.bq[1][j - l0];
        else if (j < t2) v = sm.con.bq[2][j - t1];
        else if (j < t3) v = sm.con.bq[3][j - t2];
        else {
          v = (l0 > 0) ? sm.con.bq[0][0] : (l1 > 0) ? sm.con.bq[1][0]
            : (l2 > 0) ? sm.con.bq[2][0] : (l3 > 0) ? sm.con.bq[3][0] : 0;
        }
        sm.con.s_idx[j] = v;
      }
      if (tid >= 32 && tid < 35) sm.con.s_c[tid - 32] = c3[tid - 32];
      __syncthreads();
      if (tid < 32) {
        const float* p = &xyz[((size_t)b*NPTS + sm.con.s_idx[tid])*3];
        feat[0*32+tid] = p[0] - sm.con.s_c[0];
        feat[1*32+tid] = p[1] - sm.con.s_c[1];
        feat[2*32+tid] = p[2] - sm.con.s_c[2];
      }
      {
        int r_ = tid & 31, cq_ = tid >> 5;
        const float* pr = &pts[((size_t)b*NPTS + sm.con.s_idx[r_])*64 + cq_*8];
        float4 A_ = *(const float4*)pr;
        float4 B_ = *(const float4*)(pr + 4);
        feat[(3+cq_*8+0)*32 + r_] = A_.x;
        feat[(3+cq_*8+1)*32 + r_] = A_.y;
        feat[(3+cq_*8+2)*32 + r_] = A_.z;
        feat[(3+cq_*8+3)*32 + r_] = A_.w;
        feat[(3+cq_*8+4)*32 + r_] = B_.x;
        feat[(3+cq_*8+5)*32 + r_] = B_.y;
        feat[(3+cq_*8+6)*32 + r_] = B_.z;
        feat[(3+cq_*8+7)*32 + r_] = B_.w;
      }
      __syncthreads();
      float acc[4][2] = {};
      for (int j = 0; j < C0; j++) {
        float4 av = *(const float4*)&feat[j*32 + rt*4];
        float2 wvv = *(const float2*)&w0t[j*64 + ct*2];
        float aa[4] = {av.x, av.y, av.z, av.w};
#pragma unroll
        for (int r = 0; r < 4; r++) {
          acc[r][0] = fmaf(aa[r], wvv.x, acc[r][0]);
          acc[r][1] = fmaf(aa[r], wvv.y, acc[r][1]);
        }
      }
      // stream raw x0 (pre-BN) + accumulate stats
      float* dst = x0 + row * 2048;
#pragma unroll
      for (int r = 0; r < 4; r++)
#pragma unroll
        for (int u = 0; u < 2; u++) {
          float x = acc[r][u];
          dst[(rt*4+r)*64 + ct*2+u] = x;
          s0[u] += x; q0[u] = fmaf(x, x, q0[u]);
        }
      __syncthreads();
    }
#pragma unroll
    for (int off = 1; off < 8; off <<= 1) {
#pragma unroll
      for (int u = 0; u < 2; u++) { s0[u] += __shfl_xor(s0[u], off, 64); q0[u] += __shfl_xor(q0[u], off, 64); }
    }
    if (rt == 0) {
#pragma unroll
      for (int u = 0; u < 2; u++) {
        size_t o = ((size_t)cb * 128 + ct*2 + u) * 2;
        part[o] = s0[u]; part[o+1] = q0[u];
      }
    }
    // ---- fused fin0: last consumer block reduces partials -> statsF0 ----
    __threadfence();
    if (tid == 0) {
      unsigned old = __hip_atomic_fetch_add(ctr0, 1u, __ATOMIC_ACQ_REL, __HIP_MEMORY_SCOPE_AGENT);
      s_last = (old == NCONS - 1);
    }
    __syncthreads();
    if (s_last) {
      __threadfence();
      if (tid < 64) {
        float s = 0.f, q = 0.f;
        for (int k = 0; k < NCONS; k++) {
          s += part[((size_t)k * 128 + tid) * 2];
          q += part[((size_t)k * 128 + tid) * 2 + 1];
        }
        const float inv = 1.0f / (float)NTOT;
        float mean = s * inv;
        float var = q * inv - mean * mean;
        float a = g0[tid] / sqrtf(var + 1e-5f);
        float bb = be0[tid] - mean * a;
        statsF[tid*2] = a; statsF[tid*2 + 1] = bb;
      }
    }
  }
}

// L1 pass (path A): read x0, BN0+ReLU, L1 GEMM; store raw x1 IN PLACE over x0
// (group-exclusive ownership; x0 dead afterwards); stats1; fused fin1.
__global__ __launch_bounds__(256) void k_l1x(
    float* __restrict__ x0, const float* __restrict__ w1,
    const float* __restrict__ g1, const float* __restrict__ be1,
    float* __restrict__ statsF, float* __restrict__ part,
    unsigned* __restrict__ sync) {
  __shared__ __align__(16) float w1t[64*64];
  __shared__ __align__(16) float x0n[64*32];
  __shared__ float sF[128];
  __shared__ int s_last;
  unsigned* ctr1 = sync + 9;
  int tid = threadIdx.x;
  for (int t = tid; t < 64*64; t += 256) { int j = t >> 6, c = t & 63; w1t[t] = w1[c*64 + j]; }
  if (tid < 64) { sF[tid] = statsF[tid*2]; sF[64+tid] = statsF[tid*2+1]; }
  int rt = tid & 7, ct = tid >> 3;
  float s1[2] = {0,0}, q1[2] = {0,0};
  for (int g = 0; g < 32; g++) {
    size_t gid = (size_t)blockIdx.x * 32 + g;
    __syncthreads();   // protect x0n reuse
    float* src = x0 + gid * 2048;
#pragma unroll
    for (int i = 0; i < 2; i++) {
      int local = tid*8 + i*4;
      float4 v = *(const float4*)(src + local);
      int row = local >> 6, col = local & 63;
      x0n[(col+0)*32+row] = fmaxf(0.f, fmaf(v.x, sF[col+0], sF[64+col+0]));
      x0n[(col+1)*32+row] = fmaxf(0.f, fmaf(v.y, sF[col+1], sF[64+col+1]));
      x0n[(col+2)*32+row] = fmaxf(0.f, fmaf(v.z, sF[col+2], sF[64+col+2]));
      x0n[(col+3)*32+row] = fmaxf(0.f, fmaf(v.w, sF[col+3], sF[64+col+3]));
    }
    __syncthreads();
    float acc[4][2] = {};
    for (int j = 0; j < 64; j++) {
      float4 av = *(const float4*)&x0n[j*32 + rt*4];
      float2 wv = *(const float2*)&w1t[j*64 + ct*2];
      float aa[4] = {av.x, av.y, av.z, av.w};
#pragma unroll
      for (int r = 0; r < 4; r++) {
        acc[r][0] = fmaf(aa[r], wv.x, acc[r][0]);
        acc[r][1] = fmaf(aa[r], wv.y, acc[r][1]);
      }
    }
    // store raw x1 in place (consumed only by k_l2x) + stats
#pragma unroll
    for (int r = 0; r < 4; r++)
#pragma unroll
      for (int u = 0; u < 2; u++) {
        float x = acc[r][u];
        src[(rt*4+r)*64 + ct*2+u] = x;
        s1[u] += x; q1[u] = fmaf(x, x, q1[u]);
      }
  }
#pragma unroll
  for (int off = 1; off < 8; off <<= 1) {
#pragma unroll
    for (int u = 0; u < 2; u++) { s1[u] += __shfl_xor(s1[u], off, 64); q1[u] += __shfl_xor(q1[u], off, 64); }
  }
  if (rt == 0) {
#pragma unroll
    for (int u = 0; u < 2; u++) {
      size_t o = ((size_t)blockIdx.x * 128 + ct*2 + u) * 2;
      part[o] = s1[u]; part[o+1] = q1[u];
    }
  }
  __threadfence();
  if (tid == 0) {
    unsigned old = __hip_atomic_fetch_add(ctr1, 1u, __ATOMIC_ACQ_REL, __HIP_MEMORY_SCOPE_AGENT);
    s_last = (old == 511);
  }
  __syncthreads();
  if (s_last) {
    __threadfence();
    if (tid < 64) {
      float s = 0.f, q = 0.f;
      for (int k = 0; k < 512; k++) {
        s += part[((size_t)k * 128 + tid) * 2];
        q += part[((size_t)k * 128 + tid) * 2 + 1];
      }
      const float inv = 1.0f / (float)NTOT;
      float mean = s * inv;
      float var = q * inv - mean * mean;
      float a = g1[tid] / sqrtf(var + 1e-5f);
      float bb = be1[tid] - mean * a;
      statsF[(128 + tid)*2] = a; statsF[(128 + tid)*2 + 1] = bb;
    }
  }
}

// L2 pass (path A, SLIM): read raw x1 (in x0 buffer), BN1+ReLU, L2 GEMM only;
// stats2 + per-group max/min; fused fin2.
__global__ __launch_bounds__(256) void k_l2x(
    const float* __restrict__ x1, const float* __restrict__ w2,
    const float* __restrict__ g2, const float* __restrict__ be2,
    float* __restrict__ statsF, float* __restrict__ part,
    float* __restrict__ maxb, float* __restrict__ minb,
    unsigned* __restrict__ sync) {
  __shared__ __align__(16) float w2t[64*128];
  __shared__ __align__(16) float x1n[64*32];
  __shared__ float sF[128];
  __shared__ int s_last;
  unsigned* ctr2 = sync + 10;
  int tid = threadIdx.x;
  for (int t = tid; t < 64*128; t += 256) { int j = t >> 7, c = t & 127; w2t[t] = w2[c*64 + j]; }
  if (tid < 64) { sF[tid] = statsF[(128+tid)*2]; sF[64+tid] = statsF[(128+tid)*2+1]; }
  int rt = tid & 7, ct = tid >> 3;
  float s2[4] = {0,0,0,0}, q2[4] = {0,0,0,0};
  for (int g = 0; g < 64; g++) {
    size_t gid = (size_t)blockIdx.x * 64 + g;
    __syncthreads();   // protect x1n reuse; covers sF/w2t on first iter
    const float* src = x1 + gid * 2048;
#pragma unroll
    for (int i = 0; i < 2; i++) {
      int local = tid*8 + i*4;
      float4 v = *(const float4*)(src + local);
      int row = local >> 6, col = local & 63;
      x1n[(col+0)*32+row] = fmaxf(0.f, fmaf(v.x, sF[col+0], sF[64+col+0]));
      x1n[(col+1)*32+row] = fmaxf(0.f, fmaf(v.y, sF[col+1], sF[64+col+1]));
      x1n[(col+2)*32+row] = fmaxf(0.f, fmaf(v.z, sF[col+2], sF[64+col+2]));
      x1n[(col+3)*32+row] = fmaxf(0.f, fmaf(v.w, sF[col+3], sF[64+col+3]));
    }
    __syncthreads();
    float acc[4][4] = {};
    for (int j = 0; j < 64; j++) {
      float4 av = *(const float4*)&x1n[j*32 + rt*4];
      float4 wvv = *(const float4*)&w2t[j*128 + ct*4];
      float aa[4] = {av.x, av.y, av.z, av.w};
      float ww[4] = {wvv.x, wvv.y, wvv.z, wvv.w};
#pragma unroll
      for (int r = 0; r < 4; r++)
#pragma unroll
        for (int u = 0; u < 4; u++) acc[r][u] = fmaf(aa[r], ww[u], acc[r][u]);
    }
    float mx[4], mn[4];
#pragma unroll
    for (int u = 0; u < 4; u++) {
      float x0v = acc[0][u], x1v = acc[1][u], x2v = acc[2][u], x3v = acc[3][u];
      s2[u] += ((x0v + x1v) + (x2v + x3v));
      q2[u] = fmaf(x0v, x0v, q2[u]); q2[u] = fmaf(x1v, x1v, q2[u]);
      q2[u] = fmaf(x2v, x2v, q2[u]); q2[u] = fmaf(x3v, x3v, q2[u]);
      mx[u] = fmaxf(fmaxf(x0v, x1v), fmaxf(x2v, x3v));
      mn[u] = fminf(fminf(x0v, x1v), fminf(x2v, x3v));
    }
#pragma unroll
    for (int off = 1; off < 8; off <<= 1) {
#pragma unroll
      for (int u = 0; u < 4; u++) {
        mx[u] = fmaxf(mx[u], __shfl_xor(mx[u], off, 64));
        mn[u] = fminf(mn[u], __shfl_xor(mn[u], off, 64));
      }
    }
    if (rt == 0) {
#pragma unroll
      for (int u = 0; u < 4; u++) {
        maxb[gid*128 + ct*4 + u] = mx[u];
        minb[gid*128 + ct*4 + u] = mn[u];
      }
    }
  }
#pragma unroll
  for (int off = 1; off < 8; off <<= 1) {
#pragma unroll
    for (int u = 0; u < 4; u++) { s2[u] += __shfl_xor(s2[u], off, 64); q2[u] += __shfl_xor(q2[u], off, 64); }
  }
  if (rt == 0) {
#pragma unroll
    for (int u = 0; u < 4; u++) {
      size_t o = ((size_t)blockIdx.x * 128 + ct*4 + u) * 2;
      part[o] = s2[u]; part[o+1] = q2[u];
    }
  }
  __threadfence();
  if (tid == 0) {
    unsigned old = __hip_atomic_fetch_add(ctr2, 1u, __ATOMIC_ACQ_REL, __HIP_MEMORY_SCOPE_AGENT);
    s_last = (old == 255);
  }
  __syncthreads();
  if (s_last) {
    __threadfence();
    if (tid < 128) {
      float s = 0.f, q = 0.f;
      for (int k = 0; k < 256; k++) {
        s += part[((size_t)k * 128 + tid) * 2];
        q += part[((size_t)k * 128 + tid) * 2 + 1];
      }
      const float inv = 1.0f / (float)NTOT;
      float mean = s * inv;
      float var = q * inv - mean * mean;
      float a = g2[tid] / sqrtf(var + 1e-5f);
      float bb = be2[tid] - mean * a;
      statsF[(256 + tid)*2] = a; statsF[(256 + tid)*2 + 1] = bb;
    }
  }
}

// Pool epilogue: pooled = relu(a*X + beta), X = a>=0 ? max : min.
__global__ __launch_bounds__(256) void k_pool(const float* __restrict__ maxb,
                                              const float* __restrict__ minb,
                                              const float* __restrict__ statsF,
                                              float* __restrict__ outp) {
  int t = blockIdx.x * 256 + threadIdx.x;
  int c = t & 127;
  float a  = statsF[(2*128 + c)*2];
  float bb = statsF[(2*128 + c)*2 + 1];
  float X = (a >= 0.f) ? maxb[t] : minb[t];
  outp[t] = fmaxf(0.f, fmaf(a, X, bb));
}

// ---------------------------------------------------------------------------
extern "C" void kernel_launch(void* const* d_in, const int* in_sizes, int n_in,
                              void* d_out, int out_size, void* d_ws, size_t ws_size,
                              hipStream_t stream) {
  (void)in_sizes; (void)n_in; (void)out_size; (void)ws_size;
  const float* xyz = (const float*)d_in[0];
  const float* pts = (const float*)d_in[1];
  const float* w0  = (const float*)d_in[2];
  const float* g0  = (const float*)d_in[4];
  const float* be0 = (const float*)d_in[5];
  const float* w1  = (const float*)d_in[6];
  const float* g1  = (const float*)d_in[8];
  const float* be1 = (const float*)d_in[9];
  const float* w2  = (const float*)d_in[10];
  const float* g2  = (const float*)d_in[12];
  const float* be2 = (const float*)d_in[13];

  float* out = (float*)d_out;
  float* newxyz = out;
  float* pooled = out + (size_t)NB*NS*3;

  float* ws = (float*)d_ws;
  // Path A layout (proven to fit): pp | x0 | part | statsF | maxb | minb | sync
  float* pp     = ws;                                  // 65536
  float* x0     = ws + 65536;                          // 33,554,432 (x1 in place later)
  float* part   = x0 + 33554432;                       // 131072
  float* statsF = part + 131072;                       // 768
  float* maxb   = statsF + 768;                        // 2,097,152
  float* minb   = maxb + 2097152;                      // 2,097,152
  unsigned* sync = (unsigned*)(minb + 2097152);        // prog[8], ctr0..2

  hipMemsetAsync(sync, 0, 64, stream);
  k_stage1A<<<256, 256, 0, stream>>>(xyz, pts, w0, g0, be0,
                                     newxyz, pp, x0, part, statsF, sync);
  k_l1x<<<512, 256, 0, stream>>>(x0, w1, g1, be1, statsF, part, sync);
  k_l2x<<<256, 256, 0, stream>>>(x0, w2, g2, be2, statsF, part,
                                 maxb, minb, sync);
  k_pool<<<8192, 256, 0, stream>>>(maxb, minb, statsF, pooled);
}